// Round 13
// baseline (1417.997 us; speedup 1.0000x reference)
//
#include <hip/hip_runtime.h>

#define B_   8
#define C_   96
#define H_   160
#define W_   320
#define ND   9
#define NDD  81
#define TH   16
#define TW   32                 // 8 px/thread: 64 lanes = 16 rows x 4 col-groups of 8
#define KC   4                  // channels per chunk
#define NCH  24
#define F2ROWS 18               // rows r0 .. r0+17
#define F2STRIDE 40             // 40 halo cols (32 + 2*4), exact, no pad
#define F2PLANE (F2ROWS*F2STRIDE)   // 720 dw per channel = 180 16B segments
#define BUFW (KC*F2PLANE)           // 2880 dw = 11520 B
#define NBUF 2
// LDS padded to 26624 B -> exactly 6 blocks/CU (18 waves, 4.5/SIMD) and
// regalloc cap 512/5 ~= 102 regs > ~76 demand (validated allocator model).
#define LDSWORDS 6656               // 26624 B; payload = 2*BUFW = 5760 dw

#define AS1 __attribute__((address_space(1)))
#define AS3 __attribute__((address_space(3)))

__device__ __forceinline__ void gld16(const float* gp, float* lp) {
    // HBM/L2 -> LDS direct; LDS dest = wave-uniform base + lane*16
    __builtin_amdgcn_global_load_lds((const AS1 float*)gp,
                                     (AS3 float*)(unsigned long long)lp, 16, 0, 0);
}

__global__ __launch_bounds__(192, 5)
void corr_kernel(const float* __restrict__ f1g,
                 const float* __restrict__ f2g,
                 float* __restrict__ out)
{
    __shared__ float lds[LDSWORDS];

    const int tid  = threadIdx.x;
    const int wave = tid >> 6;          // dh-within-group AND staging part index
    const int lane = tid & 63;
    const int row  = lane >> 2;         // 0..15
    const int colb = (lane & 3) << 3;   // 0,8,16,24: 8 px per thread

    // XCD swizzle: 2400 = 8 XCDs x 300 (bijective). XCD owns batch b; the 3
    // dh-groups of a tile are dispatch-adjacent (halo/L2 reuse).
    const int bid  = blockIdx.x;
    const int ebid = (bid & 7) * 300 + (bid >> 3);
    const int b    = ebid / 300;
    const int t3   = ebid - b * 300;
    const int g    = t3 % 3;            // dh = 3g + wave
    const int tile = t3 / 3;            // 0..99
    const int by   = tile / 10, bx = tile - by * 10;
    const int x0 = bx * TW, y0 = by * TH;
    const int HWi  = H_ * W_;
    const int r0   = y0 + 3 * g - 4;    // first f2 halo row (global)

    const float* f1b = f1g + (size_t)b * C_ * HWi;
    const float* f2b = f2g + (size_t)b * C_ * HWi;

    // f1: direct global->reg, thread's own 8 px
    const float* f1p = f1b + (y0 + row) * W_ + x0 + colb;

    // f2 staging: plane = 180 16B segments; seg s -> lds dw 4s, r = s/10,
    // c4 = s%10 (halo col 4*c4). Wave w stages part w: s = 64w + lane
    // (part 2 active for lane<52). Halo x-offset (4) == segment width ->
    // a segment is fully in or fully out: gx in [0, W-4] exact.
    int soW; bool ppW;
    {
        const int s  = (wave << 6) + lane;
        const int r  = s / 10, c4 = s - 10 * r;
        const int gy = r0 + r, gx = x0 - 4 + (c4 << 2);
        ppW = (s < 180) & (gy >= 0) & (gy < H_) & (gx >= 0) & (gx <= W_ - 4);
        soW = gy * W_ + gx;
    }
    const int partoff = wave << 8;      // lds dw offset of this wave's part (0,256,512)

    // compute-side read base: f2 lds row = out_row + wave, cols colb..colb+15
    const int o0 = (row + wave) * F2STRIDE + colb;

    // stage chunk cb..cb+3: wave w issues exactly 4 predicated gld16
    auto stage = [&](int cb, int bufb) {
#pragma unroll
        for (int c = 0; c < KC; ++c) {
            if (ppW) gld16(f2b + (cb + c) * HWi + soW,
                           &lds[bufb + c * F2PLANE + partoff]);
        }
    };

    // ---- accumulators: 9 offsets x 8 px (A = px0-3, B = px4-7) ----
    float4 accA0, accA1, accA2, accA3, accA4, accA5, accA6, accA7, accA8;
    float4 accB0, accB1, accB2, accB3, accB4, accB5, accB6, accB7, accB8;
    accA0=accA1=accA2=accA3=accA4=accA5=accA6=accA7=accA8 = make_float4(0.f,0.f,0.f,0.f);
    accB0=accB1=accB2=accB3=accB4=accB5=accB6=accB7=accB8 = make_float4(0.f,0.f,0.f,0.f);
    float4 PA0, PA1, PA2, PA3, PB0, PB1, PB2, PB3;

#define F1LOAD(cb) {                                              \
        PA0 = *(const float4*)(f1p + (cb) * HWi);                 \
        PB0 = *(const float4*)(f1p + (cb) * HWi + 4);             \
        PA1 = *(const float4*)(f1p + ((cb)+1) * HWi);             \
        PB1 = *(const float4*)(f1p + ((cb)+1) * HWi + 4);         \
        PA2 = *(const float4*)(f1p + ((cb)+2) * HWi);             \
        PB2 = *(const float4*)(f1p + ((cb)+2) * HWi + 4);         \
        PA3 = *(const float4*)(f1p + ((cb)+3) * HWi);             \
        PB3 = *(const float4*)(f1p + ((cb)+3) * HWi + 4); }

#define STEPD(A, P, e0, e1, e2, e3)                          \
        A.x = fmaf(P.x, e0, A.x);                            \
        A.y = fmaf(P.y, e1, A.y);                            \
        A.z = fmaf(P.z, e2, A.z);                            \
        A.w = fmaf(P.w, e3, A.w);

    // window w[j] = f2 halo col (colb + j); acc_d[px p] += P[p] * w[p+d]
#define COMPC(c, RB, PA, PB) {                                                    \
        const float4 q0 = *(const float4*)&lds[(RB) + c * F2PLANE + o0];          \
        const float4 q1 = *(const float4*)&lds[(RB) + c * F2PLANE + o0 + 4];      \
        const float4 q2 = *(const float4*)&lds[(RB) + c * F2PLANE + o0 + 8];      \
        const float4 q3 = *(const float4*)&lds[(RB) + c * F2PLANE + o0 + 12];     \
        const float w[16] = {q0.x,q0.y,q0.z,q0.w,q1.x,q1.y,q1.z,q1.w,            \
                             q2.x,q2.y,q2.z,q2.w,q3.x,q3.y,q3.z,q3.w};           \
        STEPD(accA0, PA, w[0], w[1], w[2], w[3])                                  \
        STEPD(accB0, PB, w[4], w[5], w[6], w[7])                                  \
        STEPD(accA1, PA, w[1], w[2], w[3], w[4])                                  \
        STEPD(accB1, PB, w[5], w[6], w[7], w[8])                                  \
        STEPD(accA2, PA, w[2], w[3], w[4], w[5])                                  \
        STEPD(accB2, PB, w[6], w[7], w[8], w[9])                                  \
        STEPD(accA3, PA, w[3], w[4], w[5], w[6])                                  \
        STEPD(accB3, PB, w[7], w[8], w[9], w[10])                                 \
        STEPD(accA4, PA, w[4], w[5], w[6], w[7])                                  \
        STEPD(accB4, PB, w[8], w[9], w[10], w[11])                                \
        STEPD(accA5, PA, w[5], w[6], w[7], w[8])                                  \
        STEPD(accB5, PB, w[9], w[10], w[11], w[12])                               \
        STEPD(accA6, PA, w[6], w[7], w[8], w[9])                                  \
        STEPD(accB6, PB, w[10], w[11], w[12], w[13])                              \
        STEPD(accA7, PA, w[7], w[8], w[9], w[10])                                 \
        STEPD(accB7, PB, w[11], w[12], w[13], w[14])                              \
        STEPD(accA8, PA, w[8], w[9], w[10], w[11])                                \
        STEPD(accB8, PB, w[12], w[13], w[14], w[15])                              \
    }
#define CHUNK(RB) COMPC(0,RB,PA0,PB0) COMPC(1,RB,PA1,PB1) \
                  COMPC(2,RB,PA2,PB2) COMPC(3,RB,PA3,PB3)

    // one-time zero (OOB slots never DMA'd; payload rewritten every chunk)
    for (int t = tid; t < LDSWORDS; t += 192) lds[t] = 0.f;
    __syncthreads();
    stage(0, 0);                          // chunk 0 -> buf 0

#pragma unroll 1
    for (int k = 0; k < NCH; ++k) {
        __syncthreads();                  // chunk-k DMA drained (issued 1 CHUNK ago)
        F1LOAD(KC * k)                    // f1 globals BEFORE next DMAs (in-order vmcnt)
        if (k + 1 < NCH) stage(KC * (k + 1), ((k + 1) & 1) * BUFW);
        __builtin_amdgcn_sched_barrier(0);  // pin DMA issue before compute
        CHUNK((k & 1) * BUFW)
    }

    // ---- epilogue: dh = 3g + wave; out[b, dh*9+d, y0+row, x0+colb..+7] ----
    const int dh = 3 * g + wave;
    const int gy = y0 + row;
    const int gx = x0 + colb;
#define STORED(d) {                                                                 \
        float* op_ = out + (size_t)((b * NDD + dh * ND + d) * H_ + gy) * W_ + gx;   \
        *(float4*)op_ = accA##d;                                                    \
        *(float4*)(op_ + 4) = accB##d; }
    STORED(0) STORED(1) STORED(2) STORED(3) STORED(4)
    STORED(5) STORED(6) STORED(7) STORED(8)
}

extern "C" void kernel_launch(void* const* d_in, const int* in_sizes, int n_in,
                              void* d_out, int out_size, void* d_ws, size_t ws_size,
                              hipStream_t stream)
{
    const float* f1 = (const float*)d_in[0];
    const float* f2 = (const float*)d_in[1];
    float* out = (float*)d_out;
    corr_kernel<<<dim3(2400), 192, 0, stream>>>(f1, f2, out);
}

// Round 14
// 196.605 us; speedup vs baseline: 7.2124x; 7.2124x over previous
//
#include <hip/hip_runtime.h>

#define B_   8
#define C_   96
#define H_   160
#define W_   320
#define ND   9
#define NDD  81
#define TH   16
#define TW   32                 // 8 px/thread: 64 lanes = 16 rows x 4 col-groups of 8
#define KC   4                  // channels per chunk
#define NCH  24
#define F2ROWS 18               // rows r0 .. r0+17
#define F2STRIDE 44             // 40 payload cols + 4 pad; start-quad (3rW+2m)%8 -> 2-way (free)
#define F2SEGS (F2ROWS*11)          // 198 16B segments per plane
#define F2PLANE (F2ROWS*F2STRIDE)   // 792 dw per channel
#define BUFW (KC*F2PLANE)           // 3168 dw = 12672 B
#define NBUF 2
// LDS padded to 26624 B -> 6 blocks/CU (18 waves, 4.5 w/EU) -> allocator
// target 5 w/EU -> 102-reg budget > ~80 demand (R7 precedent: no spill).
// NOTE: launch_bounds 2nd arg stays 2 — R13 proved nonzero targets there
// can pin VGPR to tiny buckets (48) and spill catastrophically.
#define LDSWORDS 6656               // 26624 B; payload = 2*BUFW = 6336 dw

#define AS1 __attribute__((address_space(1)))
#define AS3 __attribute__((address_space(3)))

__device__ __forceinline__ void gld16(const float* gp, float* lp) {
    // HBM/L2 -> LDS direct; LDS dest = wave-uniform base + lane*16
    __builtin_amdgcn_global_load_lds((const AS1 float*)gp,
                                     (AS3 float*)(unsigned long long)lp, 16, 0, 0);
}

__global__ __launch_bounds__(192, 2)
void corr_kernel(const float* __restrict__ f1g,
                 const float* __restrict__ f2g,
                 float* __restrict__ out)
{
    __shared__ float lds[LDSWORDS];

    const int tid  = threadIdx.x;
    const int wave = tid >> 6;          // dh-within-group AND staging part index
    const int lane = tid & 63;
    const int row  = lane >> 2;         // 0..15
    const int colb = (lane & 3) << 3;   // 0,8,16,24: 8 px per thread

    // XCD swizzle: 2400 = 8 XCDs x 300 (bijective). XCD owns batch b; the 3
    // dh-groups of a tile are dispatch-adjacent (halo/L2 reuse).
    const int bid  = blockIdx.x;
    const int ebid = (bid & 7) * 300 + (bid >> 3);
    const int b    = ebid / 300;
    const int t3   = ebid - b * 300;
    const int g    = t3 % 3;            // dh = 3g + wave
    const int tile = t3 / 3;            // 0..99
    const int by   = tile / 10, bx = tile - by * 10;
    const int x0 = bx * TW, y0 = by * TH;
    const int HWi  = H_ * W_;
    const int r0   = y0 + 3 * g - 4;    // first f2 halo row (global)

    const float* f1b = f1g + (size_t)b * C_ * HWi;
    const float* f2b = f2g + (size_t)b * C_ * HWi;

    // f1: direct global->reg, thread's own 8 px
    const float* f1p = f1b + (y0 + row) * W_ + x0 + colb;

    // f2 staging: seg s -> lds dw 4s; r = s/11, c4 = s%11 (halo col 4*c4,
    // c4==10 is the pad column). Wave w: s = 64w+lane; wave 2 extra tail
    // s = 192+lane (lane<6). Halo x-offset (4) == segment width -> segment
    // fully in or fully out: gx in [0, W-4] exact.
    int soW, soT; bool ppW, ppT;
    {
        int s  = (wave << 6) + lane;
        int r  = s / 11, c4 = s - 11 * r;
        int gy = r0 + r, gx = x0 - 4 + (c4 << 2);
        ppW = (c4 < 10) & (gy >= 0) & (gy < H_) & (gx >= 0) & (gx <= W_ - 4);
        soW = gy * W_ + gx;
        s  = 192 + lane;
        r  = s / 11; c4 = s - 11 * r;
        gy = r0 + r; gx = x0 - 4 + (c4 << 2);
        ppT = (wave == 2) & (lane < 6) & (c4 < 10) &
              (gy >= 0) & (gy < H_) & (gx >= 0) & (gx <= W_ - 4);
        soT = gy * W_ + gx;
    }
    const int partoff = wave << 8;      // dw offset of this wave's part (0,256,512)

    // compute-side read base: f2 lds row = out_row + wave, cols colb..colb+15
    const int o0 = (row + wave) * F2STRIDE + colb;

    // stage chunk cb..cb+3
    auto stage = [&](int cb, int bufb) {
#pragma unroll
        for (int c = 0; c < KC; ++c) {
            const float* gsrc = f2b + (cb + c) * HWi;
            float* l = &lds[bufb + c * F2PLANE];
            if (ppW) gld16(gsrc + soW, l + partoff);
            if (ppT) gld16(gsrc + soT, l + 768);
        }
    };

    // ---- accumulators: 9 offsets x 8 px (A = px0-3, B = px4-7) ----
    float4 accA0, accA1, accA2, accA3, accA4, accA5, accA6, accA7, accA8;
    float4 accB0, accB1, accB2, accB3, accB4, accB5, accB6, accB7, accB8;
    accA0=accA1=accA2=accA3=accA4=accA5=accA6=accA7=accA8 = make_float4(0.f,0.f,0.f,0.f);
    accB0=accB1=accB2=accB3=accB4=accB5=accB6=accB7=accB8 = make_float4(0.f,0.f,0.f,0.f);
    float4 PA0, PA1, PA2, PA3, PB0, PB1, PB2, PB3;

#define F1LOAD(cb) {                                              \
        PA0 = *(const float4*)(f1p + (cb) * HWi);                 \
        PB0 = *(const float4*)(f1p + (cb) * HWi + 4);             \
        PA1 = *(const float4*)(f1p + ((cb)+1) * HWi);             \
        PB1 = *(const float4*)(f1p + ((cb)+1) * HWi + 4);         \
        PA2 = *(const float4*)(f1p + ((cb)+2) * HWi);             \
        PB2 = *(const float4*)(f1p + ((cb)+2) * HWi + 4);         \
        PA3 = *(const float4*)(f1p + ((cb)+3) * HWi);             \
        PB3 = *(const float4*)(f1p + ((cb)+3) * HWi + 4); }

#define STEPD(A, P, e0, e1, e2, e3)                          \
        A.x = fmaf(P.x, e0, A.x);                            \
        A.y = fmaf(P.y, e1, A.y);                            \
        A.z = fmaf(P.z, e2, A.z);                            \
        A.w = fmaf(P.w, e3, A.w);

    // window w[j] = f2 halo col (colb + j); acc_d[px p] += P[p] * w[p+d]
#define COMPC(c, RB, PA, PB) {                                                    \
        const float4 q0 = *(const float4*)&lds[(RB) + c * F2PLANE + o0];          \
        const float4 q1 = *(const float4*)&lds[(RB) + c * F2PLANE + o0 + 4];      \
        const float4 q2 = *(const float4*)&lds[(RB) + c * F2PLANE + o0 + 8];      \
        const float4 q3 = *(const float4*)&lds[(RB) + c * F2PLANE + o0 + 12];     \
        const float w[16] = {q0.x,q0.y,q0.z,q0.w,q1.x,q1.y,q1.z,q1.w,            \
                             q2.x,q2.y,q2.z,q2.w,q3.x,q3.y,q3.z,q3.w};           \
        STEPD(accA0, PA, w[0], w[1], w[2], w[3])                                  \
        STEPD(accB0, PB, w[4], w[5], w[6], w[7])                                  \
        STEPD(accA1, PA, w[1], w[2], w[3], w[4])                                  \
        STEPD(accB1, PB, w[5], w[6], w[7], w[8])                                  \
        STEPD(accA2, PA, w[2], w[3], w[4], w[5])                                  \
        STEPD(accB2, PB, w[6], w[7], w[8], w[9])                                  \
        STEPD(accA3, PA, w[3], w[4], w[5], w[6])                                  \
        STEPD(accB3, PB, w[7], w[8], w[9], w[10])                                 \
        STEPD(accA4, PA, w[4], w[5], w[6], w[7])                                  \
        STEPD(accB4, PB, w[8], w[9], w[10], w[11])                                \
        STEPD(accA5, PA, w[5], w[6], w[7], w[8])                                  \
        STEPD(accB5, PB, w[9], w[10], w[11], w[12])                               \
        STEPD(accA6, PA, w[6], w[7], w[8], w[9])                                  \
        STEPD(accB6, PB, w[10], w[11], w[12], w[13])                              \
        STEPD(accA7, PA, w[7], w[8], w[9], w[10])                                 \
        STEPD(accB7, PB, w[11], w[12], w[13], w[14])                              \
        STEPD(accA8, PA, w[8], w[9], w[10], w[11])                                \
        STEPD(accB8, PB, w[12], w[13], w[14], w[15])                              \
    }
#define CHUNK(RB) COMPC(0,RB,PA0,PB0) COMPC(1,RB,PA1,PB1) \
                  COMPC(2,RB,PA2,PB2) COMPC(3,RB,PA3,PB3)

    // one-time zero (OOB/pad slots never DMA'd; payload rewritten every chunk)
    for (int t = tid; t < LDSWORDS; t += 192) lds[t] = 0.f;
    __syncthreads();
    stage(0, 0);                          // chunk 0 -> buf 0

#pragma unroll 1
    for (int k = 0; k < NCH; ++k) {
        __syncthreads();                  // chunk-k DMA drained (issued 1 CHUNK ago)
        F1LOAD(KC * k)                    // f1 globals BEFORE next DMAs (in-order vmcnt)
        if (k + 1 < NCH) stage(KC * (k + 1), ((k + 1) & 1) * BUFW);
        __builtin_amdgcn_sched_barrier(0);  // pin DMA issue before compute
        CHUNK((k & 1) * BUFW)
    }

    // ---- epilogue: dh = 3g + wave; out[b, dh*9+d, y0+row, x0+colb..+7] ----
    const int dh = 3 * g + wave;
    const int gy = y0 + row;
    const int gx = x0 + colb;
#define STORED(d) {                                                                 \
        float* op_ = out + (size_t)((b * NDD + dh * ND + d) * H_ + gy) * W_ + gx;   \
        *(float4*)op_ = accA##d;                                                    \
        *(float4*)(op_ + 4) = accB##d; }
    STORED(0) STORED(1) STORED(2) STORED(3) STORED(4)
    STORED(5) STORED(6) STORED(7) STORED(8)
}

extern "C" void kernel_launch(void* const* d_in, const int* in_sizes, int n_in,
                              void* d_out, int out_size, void* d_ws, size_t ws_size,
                              hipStream_t stream)
{
    const float* f1 = (const float*)d_in[0];
    const float* f2 = (const float*)d_in[1];
    float* out = (float*)d_out;
    corr_kernel<<<dim3(2400), 192, 0, stream>>>(f1, f2, out);
}